// Round 6
// baseline (511.669 us; speedup 1.0000x reference)
//
#include <hip/hip_runtime.h>
#include <hip/hip_cooperative_groups.h>
#include <hip/hip_bf16.h>
#include <hip/hip_fp16.h>
#include <cstdint>

namespace cg = cooperative_groups;

// ---------- types ----------
typedef unsigned short us;
typedef us   us4 __attribute__((ext_vector_type(4)));
typedef short s8v __attribute__((ext_vector_type(8)));   // 8 bf16 (4 VGPRs) MFMA A/B frag
typedef float f4v __attribute__((ext_vector_type(4)));   // MFMA C/D frag
typedef __fp16 pk2 __attribute__((ext_vector_type(2))); // cvt_pkrtz result type

// Problem constants (B=4, S=4096, D=1024 fixed by setup_inputs)
#define BB 4
#define SS 4096
#define DD 1024
#define MM (BB * SS)      // 16384
#define NN (2 * DD)       // 2048
#define KK DD             // 1024

// GEMM tiling (measured-best 128^2 2-phase structure; 256^2 8-phase regressed)
#define BM 128
#define BN 128
#define BK 64
#define NTILES ((MM / BM) * (DD / 64))   // 2048 logical gemm tiles

// Scan chunking
#define CHUNK 32
#define NC (SS / CHUNK)   // 128
#define BDD (BB * DD)     // 4096 sequences
#define DQ (DD / 4)       // 256 channel-quads (fallback pass3)
#define NXW ((long)MM * KK + (long)NN * KK)   // total fp32 elems to convert
#define NXQ (NXW / 4)                          // float4 quads

// ---------- fp32 -> bf16 (RNE) ----------
__device__ inline us f2bf(float f) {
  unsigned u = __float_as_uint(f);
  u += 0x7fffu + ((u >> 16) & 1u);
  return (us)(u >> 16);
}

// ---------- async global->LDS, 16B per lane ----------
#define GLD16(g, l)                                                        \
  __builtin_amdgcn_global_load_lds(                                        \
      (const __attribute__((address_space(1))) void*)(g),                  \
      (__attribute__((address_space(3))) void*)(l), 16, 0, 0)

// ---------- gate math ----------
__device__ inline void gate_cv(float hid, float gat, float& coef, float& v) {
  float e = __expf(gat);
  coef = __builtin_amdgcn_rcpf(1.0f + e);      // sigmoid(-gate)
  float z = 1.0f - coef;                        // sigmoid(gate), robust at e=inf
  float eh = __expf(hid < 0.0f ? hid : 0.0f);
  float gneg = eh * __builtin_amdgcn_rcpf(1.0f + eh);
  float g = (hid >= 0.0f) ? (hid + 0.5f) : gneg;
  v = z * g;
}

// =====================================================================
// R6 mega-kernel: all four phases in one cooperative launch.
// Non-gemm time has been invariant at ~136us across 4 rounds of BW/ILP
// micro-opts while the kernels' roofline sum is ~50us -> the slack is
// inter-kernel serialization in the captured graph. Collapse it.
// Phases (byte-identical math to the R5 kernels -> absmax 0.03125):
//   1 cvt (grid-stride)  | grid.sync | 2 gemm (2 tiles/block, same x ->
//   A-panel reuse)       | grid.sync | 3 pass2 (first 4096 lanes)
//                        | grid.sync | 4 pass3 (float2 flavor, R0-proven)
// launch_bounds(256,4): caps VGPR at 128 (gemm needs 96) so 4 blocks/CU
// residency is resource-guaranteed; host clamps grid via occupancy query.
// =====================================================================
__global__ __launch_bounds__(256, 4) void mega(const float* __restrict__ x,
                                               const float* __restrict__ W,
                                               us* __restrict__ xb,
                                               us* __restrict__ wb,
                                               unsigned* __restrict__ cv,
                                               float* __restrict__ cp,
                                               float* __restrict__ ch,
                                               float* __restrict__ carry,
                                               float2* __restrict__ out) {
  cg::grid_group grid = cg::this_grid();
  const int tid  = threadIdx.x;
  const int nblk = gridDim.x;
  const long gsize = (long)nblk * 256;
  const long gtid  = (long)blockIdx.x * 256 + tid;
  const long nx = (long)MM * KK;

  // ---------------- phase 1: fp32 -> bf16 convert ----------------
  for (long q = gtid; q < NXQ; q += gsize) {
    long i = q * 4;
    const float* in;
    us* o;
    if (i < nx) { in = x + i; o = xb + i; }
    else        { in = W + (i - nx); o = wb + (i - nx); }
    float4 a = *(const float4*)in;
    us4 ov;
    ov[0] = f2bf(a.x); ov[1] = f2bf(a.y); ov[2] = f2bf(a.z); ov[3] = f2bf(a.w);
    *(us4*)o = ov;
  }
  grid.sync();

  // ---------------- phase 2: fused GEMM + gate + chunk scan ----------------
  {
    __shared__ __align__(16) us smem[BM * BK + BN * BK];  // 32 KB
    us* As = smem;
    us* Bs = smem + BM * BK;
    unsigned* T = (unsigned*)smem;    // epilogue reuse: [128 rows][64 d]

    const int lane = tid & 63;
    const int w    = tid >> 6;      // wave 0..3
    const int wm   = w & 1;         // 2x2 wave grid
    const int wn   = w >> 1;

    const int srow = lane >> 3;
    const int sseg = (lane & 7) ^ srow;
    const int fr = lane & 15;
    const int fq = lane >> 4;

    int aoff[4][2], boff[4][2];
#pragma unroll
    for (int mt = 0; mt < 4; ++mt) {
      int row = wm * 64 + mt * 16 + fr;
#pragma unroll
      for (int kk = 0; kk < 2; ++kk) {
        int seg = kk * 4 + fq;
        aoff[mt][kk] = row * BK + ((seg ^ (row & 7)) * 8);
      }
    }
#pragma unroll
    for (int nt = 0; nt < 4; ++nt) {
      int row = wn * 64 + nt * 16 + fr;
#pragma unroll
      for (int kk = 0; kk < 2; ++kk) {
        int seg = kk * 4 + fq;
        boff[nt][kk] = row * BK + ((seg ^ (row & 7)) * 8);
      }
    }

    for (int t = blockIdx.x; t < NTILES; t += nblk) {
      const int bx = t & (MM / BM - 1);        // 0..127 (same linearization
      const int by = t >> 7;                   //  as the old 2D grid)
      const long bm = (long)bx * BM;
      const int  d0 = by * 64;

      f4v acc[4][4] = {};

      const us* Ap[4];
      const us* Bp[4];
#pragma unroll
      for (int i = 0; i < 4; ++i) {
        int lr = w * 32 + i * 8 + srow;
        Ap[i] = xb + (bm + lr) * (long)KK + sseg * 8;
        int wrow = d0 + ((lr >> 5) << 4) + (lr & 15) + (((lr >> 4) & 1) << 10);
        Bp[i] = wb + (long)wrow * KK + sseg * 8;
      }

      for (int kt = 0; kt < KK / BK; ++kt) {
        __syncthreads();   // previous tile's reads done before overwrite
#pragma unroll
        for (int i = 0; i < 4; ++i) {
          GLD16(Ap[i], &As[(w * 32 + i * 8) * BK]);
          GLD16(Bp[i], &Bs[(w * 32 + i * 8) * BK]);
          Ap[i] += BK;
          Bp[i] += BK;
        }
        __syncthreads();   // staging visible

#pragma unroll
        for (int kk = 0; kk < 2; ++kk) {
          s8v af[4], bf[4];
#pragma unroll
          for (int mt = 0; mt < 4; ++mt) af[mt] = *(const s8v*)&As[aoff[mt][kk]];
#pragma unroll
          for (int nt = 0; nt < 4; ++nt) bf[nt] = *(const s8v*)&Bs[boff[nt][kk]];
#pragma unroll
          for (int mt = 0; mt < 4; ++mt)
#pragma unroll
            for (int nt = 0; nt < 4; ++nt)
              acc[mt][nt] = __builtin_amdgcn_mfma_f32_16x16x32_bf16(
                  af[mt], bf[nt], acc[mt][nt], 0, 0, 0);
        }
      }

      // ---- epilogue ----
      __syncthreads();   // all waves done with As/Bs; reuse LDS as T
#pragma unroll
      for (int mt = 0; mt < 4; ++mt) {
        int lr0 = wm * 64 + mt * 16 + fq * 4;
#pragma unroll
        for (int p = 0; p < 2; ++p) {
          int ld = (wn * 2 + p) * 16 + fr;
          f4v hv = acc[mt][2 * p];
          f4v gv = acc[mt][2 * p + 1];
#pragma unroll
          for (int r = 0; r < 4; ++r) {
            float coef, v;
            gate_cv(hv[r], gv[r], coef, v);
            pk2 pk = __builtin_amdgcn_cvt_pkrtz(coef, v);
            T[(lr0 + r) * 64 + ld] = __builtin_bit_cast(unsigned, pk);
          }
        }
      }
      __syncthreads();   // transpose complete

#pragma unroll
      for (int j = 0; j < 8; ++j) {
        int chunk = j * 256 + tid;
        int row = chunk >> 4;
        int q   = chunk & 15;
        uint4 val = *(const uint4*)&T[row * 64 + q * 4];
        *(uint4*)(cv + (size_t)(bm + row) * DD + d0 + q * 4) = val;
      }

      {
        const int d = tid & 63;
        const int c = tid >> 6;
        float P = 1.0f, h = 0.0f;
#pragma unroll
        for (int i = 0; i < CHUNK; ++i) {
          unsigned u = T[(c * CHUNK + i) * 64 + d];
          __half2 hv = *(__half2*)&u;
          float cf = __half2float(hv.x);
          h = fmaf(cf, h, __half2float(hv.y));
          P *= cf;
        }
        const int b  = (int)(bm / SS);
        const int cg2 = (int)((bm % SS) / CHUNK) + c;
        const int idx = cg2 * BDD + b * DD + d0 + d;
        cp[idx] = P;
        ch[idx] = h;
      }
    }
  }
  grid.sync();

  // ---------------- phase 3: serial chunk-summary scan ----------------
  for (long bd = gtid; bd < BDD; bd += gsize) {
    float h = 0.0f;
    for (int cb = 0; cb < NC; cb += 16) {
      float p[16], v[16];
#pragma unroll
      for (int i = 0; i < 16; ++i) {
        p[i] = cp[(cb + i) * BDD + bd];
        v[i] = ch[(cb + i) * BDD + bd];
      }
#pragma unroll
      for (int i = 0; i < 16; ++i) {
        carry[(cb + i) * BDD + bd] = h;
        h = fmaf(p[i], h, v[i]);
      }
    }
  }
  grid.sync();

  // ---------------- phase 4: re-run chunks with carry, write out ----------------
  // 1024 logical sub-blocks: (b, c, half); 256 threads x 1 channel-pair.
  for (int r = blockIdx.x; r < 1024; r += nblk) {
    const int b    = r >> 8;
    const int rem  = r & 255;
    const int c    = rem >> 1;
    const int half = rem & 1;
    const int dp   = half * 256 + tid;            // channel-pair 0..511
    const size_t rbase = ((size_t)b * SS + (size_t)c * CHUNK) * (DD / 2) + dp;
    const uint2* base = (const uint2*)cv + rbase;
    float2* obase = out + rbase;
    float2 h = *(const float2*)&carry[c * BDD + b * DD + 2 * dp];
    for (int tb = 0; tb < CHUNK; tb += 8) {
      uint2 u[8];
#pragma unroll
      for (int j = 0; j < 8; ++j) u[j] = base[(size_t)(tb + j) * (DD / 2)];
#pragma unroll
      for (int j = 0; j < 8; ++j) {
        __half2 a0 = *(__half2*)&u[j].x;
        __half2 a1 = *(__half2*)&u[j].y;
        h.x = fmaf(__half2float(a0.x), h.x, __half2float(a0.y));
        h.y = fmaf(__half2float(a1.x), h.y, __half2float(a1.y));
        obase[(size_t)(tb + j) * (DD / 2)] = h;
      }
    }
  }
}

// =====================================================================
// Fallback path: the proven R5 four-kernel pipeline (launched only if
// cooperative launch is unavailable/fails). Byte-identical numerics.
// =====================================================================
__global__ __launch_bounds__(256) void cvt_both(const float* __restrict__ x,
                                                const float* __restrict__ W,
                                                us* __restrict__ xb,
                                                us* __restrict__ wb,
                                                long nx) {
  long i = ((long)blockIdx.x * 256 + threadIdx.x) * 4;
  const float* in;
  us* out;
  if (i < nx) { in = x + i; out = xb + i; }
  else        { in = W + (i - nx); out = wb + (i - nx); }
  float4 a = *(const float4*)in;
  us4 o;
  o[0] = f2bf(a.x); o[1] = f2bf(a.y); o[2] = f2bf(a.z); o[3] = f2bf(a.w);
  *(us4*)out = o;
}

__global__ __launch_bounds__(256) void gemm_fused(const us* __restrict__ A,
                                                  const us* __restrict__ B,
                                                  unsigned* __restrict__ cv,
                                                  float* __restrict__ cp,
                                                  float* __restrict__ ch) {
  __shared__ __align__(16) us smem[BM * BK + BN * BK];
  us* As = smem;
  us* Bs = smem + BM * BK;
  unsigned* T = (unsigned*)smem;

  const int tid  = threadIdx.x;
  const int lane = tid & 63;
  const int w    = tid >> 6;
  const int wm   = w & 1;
  const int wn   = w >> 1;
  const long bm  = (long)blockIdx.x * BM;
  const int  d0  = blockIdx.y * 64;

  const int srow = lane >> 3;
  const int sseg = (lane & 7) ^ srow;
  const int fr = lane & 15;
  const int fq = lane >> 4;

  int aoff[4][2], boff[4][2];
#pragma unroll
  for (int mt = 0; mt < 4; ++mt) {
    int row = wm * 64 + mt * 16 + fr;
#pragma unroll
    for (int kk = 0; kk < 2; ++kk) {
      int seg = kk * 4 + fq;
      aoff[mt][kk] = row * BK + ((seg ^ (row & 7)) * 8);
    }
  }
#pragma unroll
  for (int nt = 0; nt < 4; ++nt) {
    int row = wn * 64 + nt * 16 + fr;
#pragma unroll
    for (int kk = 0; kk < 2; ++kk) {
      int seg = kk * 4 + fq;
      boff[nt][kk] = row * BK + ((seg ^ (row & 7)) * 8);
    }
  }

  f4v acc[4][4] = {};

  const us* Ap[4];
  const us* Bp[4];
#pragma unroll
  for (int i = 0; i < 4; ++i) {
    int lr = w * 32 + i * 8 + srow;
    Ap[i] = A + (bm + lr) * (long)KK + sseg * 8;
    int wrow = d0 + ((lr >> 5) << 4) + (lr & 15) + (((lr >> 4) & 1) << 10);
    Bp[i] = B + (long)wrow * KK + sseg * 8;
  }

  for (int kt = 0; kt < KK / BK; ++kt) {
    __syncthreads();
#pragma unroll
    for (int i = 0; i < 4; ++i) {
      GLD16(Ap[i], &As[(w * 32 + i * 8) * BK]);
      GLD16(Bp[i], &Bs[(w * 32 + i * 8) * BK]);
      Ap[i] += BK;
      Bp[i] += BK;
    }
    __syncthreads();

#pragma unroll
    for (int kk = 0; kk < 2; ++kk) {
      s8v af[4], bf[4];
#pragma unroll
      for (int mt = 0; mt < 4; ++mt) af[mt] = *(const s8v*)&As[aoff[mt][kk]];
#pragma unroll
      for (int nt = 0; nt < 4; ++nt) bf[nt] = *(const s8v*)&Bs[boff[nt][kk]];
#pragma unroll
      for (int mt = 0; mt < 4; ++mt)
#pragma unroll
        for (int nt = 0; nt < 4; ++nt)
          acc[mt][nt] = __builtin_amdgcn_mfma_f32_16x16x32_bf16(
              af[mt], bf[nt], acc[mt][nt], 0, 0, 0);
    }
  }

  __syncthreads();
#pragma unroll
  for (int mt = 0; mt < 4; ++mt) {
    int lr0 = wm * 64 + mt * 16 + fq * 4;
#pragma unroll
    for (int p = 0; p < 2; ++p) {
      int ld = (wn * 2 + p) * 16 + fr;
      f4v hv = acc[mt][2 * p];
      f4v gv = acc[mt][2 * p + 1];
#pragma unroll
      for (int r = 0; r < 4; ++r) {
        float coef, v;
        gate_cv(hv[r], gv[r], coef, v);
        pk2 pk = __builtin_amdgcn_cvt_pkrtz(coef, v);
        T[(lr0 + r) * 64 + ld] = __builtin_bit_cast(unsigned, pk);
      }
    }
  }
  __syncthreads();

#pragma unroll
  for (int j = 0; j < 8; ++j) {
    int chunk = j * 256 + tid;
    int row = chunk >> 4;
    int q   = chunk & 15;
    uint4 val = *(const uint4*)&T[row * 64 + q * 4];
    *(uint4*)(cv + (size_t)(bm + row) * DD + d0 + q * 4) = val;
  }

  {
    const int d = tid & 63;
    const int c = tid >> 6;
    float P = 1.0f, h = 0.0f;
#pragma unroll
    for (int i = 0; i < CHUNK; ++i) {
      unsigned u = T[(c * CHUNK + i) * 64 + d];
      __half2 hv = *(__half2*)&u;
      float cf = __half2float(hv.x);
      h = fmaf(cf, h, __half2float(hv.y));
      P *= cf;
    }
    const int b  = (int)(bm / SS);
    const int cg2 = (int)((bm % SS) / CHUNK) + c;
    const int idx = cg2 * BDD + b * DD + d0 + d;
    cp[idx] = P;
    ch[idx] = h;
  }
}

__global__ __launch_bounds__(256) void scan_pass2(const float* __restrict__ cp,
                                                  const float* __restrict__ ch,
                                                  float* __restrict__ carry) {
  const int bd = blockIdx.x * 256 + threadIdx.x;
  float h = 0.0f;
  for (int cb = 0; cb < NC; cb += 16) {
    float p[16], v[16];
#pragma unroll
    for (int i = 0; i < 16; ++i) {
      p[i] = cp[(cb + i) * BDD + bd];
      v[i] = ch[(cb + i) * BDD + bd];
    }
#pragma unroll
    for (int i = 0; i < 16; ++i) {
      carry[(cb + i) * BDD + bd] = h;
      h = fmaf(p[i], h, v[i]);
    }
  }
}

__global__ __launch_bounds__(256) void scan_pass3(const uint4* __restrict__ cv,
                                                  const float* __restrict__ carry,
                                                  float4* __restrict__ out) {
  const int q = threadIdx.x;
  const int c = blockIdx.y;
  const int b = blockIdx.z;
  const size_t rbase = ((size_t)b * SS + (size_t)c * CHUNK) * DQ + q;
  const uint4* base = cv + rbase;
  float4* obase = out + rbase;
  float4 h = *(const float4*)&carry[c * BDD + b * DD + 4 * q];
  for (int tb = 0; tb < CHUNK; tb += 8) {
    uint4 u[8];
#pragma unroll
    for (int j = 0; j < 8; ++j) u[j] = base[(size_t)(tb + j) * DQ];
#pragma unroll
    for (int j = 0; j < 8; ++j) {
      __half2 a0 = *(__half2*)&u[j].x;
      __half2 a1 = *(__half2*)&u[j].y;
      __half2 a2 = *(__half2*)&u[j].z;
      __half2 a3 = *(__half2*)&u[j].w;
      h.x = fmaf(__half2float(a0.x), h.x, __half2float(a0.y));
      h.y = fmaf(__half2float(a1.x), h.y, __half2float(a1.y));
      h.z = fmaf(__half2float(a2.x), h.z, __half2float(a2.y));
      h.w = fmaf(__half2float(a3.x), h.w, __half2float(a3.y));
      obase[(size_t)(tb + j) * DQ] = h;
    }
  }
}

// ---------- launch ----------
extern "C" void kernel_launch(void* const* d_in, const int* in_sizes, int n_in,
                              void* d_out, int out_size, void* d_ws, size_t ws_size,
                              hipStream_t stream) {
  const float* x = (const float*)d_in[0];   // [4,4096,1024] fp32
  const float* W = (const float*)d_in[1];   // [2048,1024]  fp32

  const long nx = (long)MM * KK;            // 16,777,216
  const long nw = (long)NN * KK;            //  2,097,152

  // workspace layout (~106 MiB total)
  char* ws = (char*)d_ws;
  unsigned* cv = (unsigned*)ws;      ws += (size_t)MM * DD * sizeof(unsigned); // 64 MiB
  us* xb = (us*)ws;                  ws += (size_t)nx * sizeof(us);            // 32 MiB
  us* wb = (us*)ws;                  ws += (size_t)nw * sizeof(us);            //  4 MiB
  float* cp = (float*)ws;            ws += (size_t)NC * BDD * sizeof(float);   //  2 MiB
  float* chh = (float*)ws;           ws += (size_t)NC * BDD * sizeof(float);   //  2 MiB
  float* carry = (float*)ws;         ws += (size_t)NC * BDD * sizeof(float);   //  2 MiB

  // one-time cooperative capability + occupancy probe (host-only queries,
  // no stream ops -> graph-capture-safe)
  static int s_coop = -1;
  if (s_coop < 0) {
    s_coop = 0;
    int dev = 0;
    hipGetDevice(&dev);
    hipDeviceProp_t prop{};
    if (hipGetDeviceProperties(&prop, dev) == hipSuccess && prop.cooperativeLaunch) {
      int perCU = 0;
      if (hipOccupancyMaxActiveBlocksPerMultiprocessor(
              &perCU, (const void*)mega, 256, 0) == hipSuccess && perCU >= 1) {
        long cap = (long)perCU * prop.multiProcessorCount;
        s_coop = (int)(cap < 1024 ? cap : 1024);
      }
    }
    if (s_coop < 16) s_coop = 0;   // need >=4096 threads for phase 3
  }

  if (s_coop > 0) {
    const float* xl = x; const float* Wl = W;
    us* xbl = xb; us* wbl = wb;
    unsigned* cvl = cv;
    float* cpl = cp; float* chl = chh; float* cal = carry;
    float2* outl = (float2*)d_out;
    void* args[] = {&xl, &Wl, &xbl, &wbl, &cvl, &cpl, &chl, &cal, &outl};
    if (hipLaunchCooperativeKernel((void*)mega, dim3(s_coop), dim3(256),
                                   args, 0, stream) == hipSuccess)
      return;
    s_coop = 0;   // launch rejected: don't retry, fall through
  }

  // fallback: proven R5 four-kernel pipeline
  cvt_both<<<(int)((nx + nw) / 4 / 256), 256, 0, stream>>>(x, W, xb, wb, nx);
  gemm_fused<<<dim3(MM / BM, DD / 64), 256, 0, stream>>>(xb, wb, cv, cp, chh);
  scan_pass2<<<dim3(BDD / 256), 256, 0, stream>>>(cp, chh, carry);
  scan_pass3<<<dim3(1, NC, BB), 256, 0, stream>>>((const uint4*)cv, carry,
                                                  (float4*)d_out);
}

// Round 7
// 224.383 us; speedup vs baseline: 2.2803x; 2.2803x over previous
//
#include <hip/hip_runtime.h>
#include <hip/hip_cooperative_groups.h>
#include <hip/hip_bf16.h>
#include <hip/hip_fp16.h>
#include <cstdint>

namespace cg = cooperative_groups;

// ---------- types ----------
typedef unsigned short us;
typedef us   us4 __attribute__((ext_vector_type(4)));
typedef short s8v __attribute__((ext_vector_type(8)));   // 8 bf16 (4 VGPRs) MFMA A/B frag
typedef float f4v __attribute__((ext_vector_type(4)));   // MFMA C/D frag
typedef __fp16 pk2 __attribute__((ext_vector_type(2))); // cvt_pkrtz result type

// Problem constants (B=4, S=4096, D=1024 fixed by setup_inputs)
#define BB 4
#define SS 4096
#define DD 1024
#define MM (BB * SS)      // 16384
#define NN (2 * DD)       // 2048
#define KK DD             // 1024

// GEMM tiling (measured-best 128^2 2-phase structure; 256^2 8-phase regressed)
#define BM 128
#define BN 128
#define BK 64
#define NTILES ((MM / BM) * (DD / 64))   // 2048 logical gemm tiles

// Scan chunking
#define CHUNK 32
#define NC (SS / CHUNK)   // 128
#define BDD (BB * DD)     // 4096 sequences
#define DQ (DD / 4)       // 256 channel-quads (fallback pass3)
#define NXW ((long)MM * KK + (long)NN * KK)   // total fp32 elems to convert
#define NXQ (NXW / 4)                          // float4 quads

// ---------- fp32 -> bf16 (RNE) ----------
__device__ inline us f2bf(float f) {
  unsigned u = __float_as_uint(f);
  u += 0x7fffu + ((u >> 16) & 1u);
  return (us)(u >> 16);
}

// ---------- async global->LDS, 16B per lane ----------
#define GLD16(g, l)                                                        \
  __builtin_amdgcn_global_load_lds(                                        \
      (const __attribute__((address_space(1))) void*)(g),                  \
      (__attribute__((address_space(3))) void*)(l), 16, 0, 0)

// ---------- gate math ----------
__device__ inline void gate_cv(float hid, float gat, float& coef, float& v) {
  float e = __expf(gat);
  coef = __builtin_amdgcn_rcpf(1.0f + e);      // sigmoid(-gate)
  float z = 1.0f - coef;                        // sigmoid(gate), robust at e=inf
  float eh = __expf(hid < 0.0f ? hid : 0.0f);
  float gneg = eh * __builtin_amdgcn_rcpf(1.0f + eh);
  float g = (hid >= 0.0f) ? (hid + 0.5f) : gneg;
  v = z * g;
}

// =====================================================================
// R7 mega-kernel v2. R6's regression was register starvation, not the
// concept: __launch_bounds__(256,4) capped unified VGPR+AGPR at 128,
// leaving 64 VGPRs (vs the 96 the GEMM needs) -> inner-loop spills
// (+95MB scratch WRITE_SIZE, 565us). Fix: plain __launch_bounds__(256)
// so the compiler allocates like the proven standalone gemm (~96 VGPR +
// 64 AGPR); the host occupancy query sizes the cooperative grid to the
// co-resident capacity at that allocation (phases are grid-stride, any
// grid size is correct; need >=16 blocks for phase 3's 4096 lanes).
// Phases (byte-identical math to the R5 kernels -> absmax 0.03125):
//   1 cvt | grid.sync | 2 gemm | grid.sync | 3 pass2 | grid.sync | 4 pass3
// =====================================================================
__global__ __launch_bounds__(256) void mega(const float* __restrict__ x,
                                            const float* __restrict__ W,
                                            us* __restrict__ xb,
                                            us* __restrict__ wb,
                                            unsigned* __restrict__ cv,
                                            float* __restrict__ cp,
                                            float* __restrict__ ch,
                                            float* __restrict__ carry,
                                            float2* __restrict__ out) {
  cg::grid_group grid = cg::this_grid();
  const int tid  = threadIdx.x;
  const int nblk = gridDim.x;
  const long gsize = (long)nblk * 256;
  const long gtid  = (long)blockIdx.x * 256 + tid;
  const long nx = (long)MM * KK;

  // ---------------- phase 1: fp32 -> bf16 convert ----------------
  for (long q = gtid; q < NXQ; q += gsize) {
    long i = q * 4;
    const float* in;
    us* o;
    if (i < nx) { in = x + i; o = xb + i; }
    else        { in = W + (i - nx); o = wb + (i - nx); }
    float4 a = *(const float4*)in;
    us4 ov;
    ov[0] = f2bf(a.x); ov[1] = f2bf(a.y); ov[2] = f2bf(a.z); ov[3] = f2bf(a.w);
    *(us4*)o = ov;
  }
  grid.sync();

  // ---------------- phase 2: fused GEMM + gate + chunk scan ----------------
  {
    __shared__ __align__(16) us smem[BM * BK + BN * BK];  // 32 KB
    us* As = smem;
    us* Bs = smem + BM * BK;
    unsigned* T = (unsigned*)smem;    // epilogue reuse: [128 rows][64 d]

    const int lane = tid & 63;
    const int w    = tid >> 6;      // wave 0..3
    const int wm   = w & 1;         // 2x2 wave grid
    const int wn   = w >> 1;

    const int srow = lane >> 3;
    const int sseg = (lane & 7) ^ srow;
    const int fr = lane & 15;
    const int fq = lane >> 4;

    int aoff[4][2], boff[4][2];
#pragma unroll
    for (int mt = 0; mt < 4; ++mt) {
      int row = wm * 64 + mt * 16 + fr;
#pragma unroll
      for (int kk = 0; kk < 2; ++kk) {
        int seg = kk * 4 + fq;
        aoff[mt][kk] = row * BK + ((seg ^ (row & 7)) * 8);
      }
    }
#pragma unroll
    for (int nt = 0; nt < 4; ++nt) {
      int row = wn * 64 + nt * 16 + fr;
#pragma unroll
      for (int kk = 0; kk < 2; ++kk) {
        int seg = kk * 4 + fq;
        boff[nt][kk] = row * BK + ((seg ^ (row & 7)) * 8);
      }
    }

    for (int t = blockIdx.x; t < NTILES; t += nblk) {
      const int bx = t & (MM / BM - 1);        // 0..127 (same linearization
      const int by = t >> 7;                   //  as the old 2D grid)
      const long bm = (long)bx * BM;
      const int  d0 = by * 64;

      f4v acc[4][4] = {};

      const us* Ap[4];
      const us* Bp[4];
#pragma unroll
      for (int i = 0; i < 4; ++i) {
        int lr = w * 32 + i * 8 + srow;
        Ap[i] = xb + (bm + lr) * (long)KK + sseg * 8;
        int wrow = d0 + ((lr >> 5) << 4) + (lr & 15) + (((lr >> 4) & 1) << 10);
        Bp[i] = wb + (long)wrow * KK + sseg * 8;
      }

      for (int kt = 0; kt < KK / BK; ++kt) {
        __syncthreads();   // previous tile's reads done before overwrite
#pragma unroll
        for (int i = 0; i < 4; ++i) {
          GLD16(Ap[i], &As[(w * 32 + i * 8) * BK]);
          GLD16(Bp[i], &Bs[(w * 32 + i * 8) * BK]);
          Ap[i] += BK;
          Bp[i] += BK;
        }
        __syncthreads();   // staging visible

#pragma unroll
        for (int kk = 0; kk < 2; ++kk) {
          s8v af[4], bf[4];
#pragma unroll
          for (int mt = 0; mt < 4; ++mt) af[mt] = *(const s8v*)&As[aoff[mt][kk]];
#pragma unroll
          for (int nt = 0; nt < 4; ++nt) bf[nt] = *(const s8v*)&Bs[boff[nt][kk]];
#pragma unroll
          for (int mt = 0; mt < 4; ++mt)
#pragma unroll
            for (int nt = 0; nt < 4; ++nt)
              acc[mt][nt] = __builtin_amdgcn_mfma_f32_16x16x32_bf16(
                  af[mt], bf[nt], acc[mt][nt], 0, 0, 0);
        }
      }

      // ---- epilogue ----
      __syncthreads();   // all waves done with As/Bs; reuse LDS as T
#pragma unroll
      for (int mt = 0; mt < 4; ++mt) {
        int lr0 = wm * 64 + mt * 16 + fq * 4;
#pragma unroll
        for (int p = 0; p < 2; ++p) {
          int ld = (wn * 2 + p) * 16 + fr;
          f4v hv = acc[mt][2 * p];
          f4v gv = acc[mt][2 * p + 1];
#pragma unroll
          for (int r = 0; r < 4; ++r) {
            float coef, v;
            gate_cv(hv[r], gv[r], coef, v);
            pk2 pk = __builtin_amdgcn_cvt_pkrtz(coef, v);
            T[(lr0 + r) * 64 + ld] = __builtin_bit_cast(unsigned, pk);
          }
        }
      }
      __syncthreads();   // transpose complete

#pragma unroll
      for (int j = 0; j < 8; ++j) {
        int chunk = j * 256 + tid;
        int row = chunk >> 4;
        int q   = chunk & 15;
        uint4 val = *(const uint4*)&T[row * 64 + q * 4];
        *(uint4*)(cv + (size_t)(bm + row) * DD + d0 + q * 4) = val;
      }

      {
        const int d = tid & 63;
        const int c = tid >> 6;
        float P = 1.0f, h = 0.0f;
#pragma unroll
        for (int i = 0; i < CHUNK; ++i) {
          unsigned u = T[(c * CHUNK + i) * 64 + d];
          __half2 hv = *(__half2*)&u;
          float cf = __half2float(hv.x);
          h = fmaf(cf, h, __half2float(hv.y));
          P *= cf;
        }
        const int b  = (int)(bm / SS);
        const int cg2 = (int)((bm % SS) / CHUNK) + c;
        const int idx = cg2 * BDD + b * DD + d0 + d;
        cp[idx] = P;
        ch[idx] = h;
      }
    }
  }
  grid.sync();

  // ---------------- phase 3: serial chunk-summary scan ----------------
  for (long bd = gtid; bd < BDD; bd += gsize) {
    float h = 0.0f;
    for (int cb = 0; cb < NC; cb += 16) {
      float p[16], v[16];
#pragma unroll
      for (int i = 0; i < 16; ++i) {
        p[i] = cp[(cb + i) * BDD + bd];
        v[i] = ch[(cb + i) * BDD + bd];
      }
#pragma unroll
      for (int i = 0; i < 16; ++i) {
        carry[(cb + i) * BDD + bd] = h;
        h = fmaf(p[i], h, v[i]);
      }
    }
  }
  grid.sync();

  // ---------------- phase 4: re-run chunks with carry, write out ----------------
  // 1024 logical sub-blocks: (b, c, half); 256 threads x 1 channel-pair.
  for (int r = blockIdx.x; r < 1024; r += nblk) {
    const int b    = r >> 8;
    const int rem  = r & 255;
    const int c    = rem >> 1;
    const int half = rem & 1;
    const int dp   = half * 256 + tid;            // channel-pair 0..511
    const size_t rbase = ((size_t)b * SS + (size_t)c * CHUNK) * (DD / 2) + dp;
    const uint2* base = (const uint2*)cv + rbase;
    float2* obase = out + rbase;
    float2 h = *(const float2*)&carry[c * BDD + b * DD + 2 * dp];
    for (int tb = 0; tb < CHUNK; tb += 8) {
      uint2 u[8];
#pragma unroll
      for (int j = 0; j < 8; ++j) u[j] = base[(size_t)(tb + j) * (DD / 2)];
#pragma unroll
      for (int j = 0; j < 8; ++j) {
        __half2 a0 = *(__half2*)&u[j].x;
        __half2 a1 = *(__half2*)&u[j].y;
        h.x = fmaf(__half2float(a0.x), h.x, __half2float(a0.y));
        h.y = fmaf(__half2float(a1.x), h.y, __half2float(a1.y));
        obase[(size_t)(tb + j) * (DD / 2)] = h;
      }
    }
  }
}

// =====================================================================
// Fallback path: the proven R5 four-kernel pipeline (launched only if
// cooperative launch is unavailable/fails). Byte-identical numerics.
// =====================================================================
__global__ __launch_bounds__(256) void cvt_both(const float* __restrict__ x,
                                                const float* __restrict__ W,
                                                us* __restrict__ xb,
                                                us* __restrict__ wb,
                                                long nx) {
  long i = ((long)blockIdx.x * 256 + threadIdx.x) * 4;
  const float* in;
  us* out;
  if (i < nx) { in = x + i; out = xb + i; }
  else        { in = W + (i - nx); out = wb + (i - nx); }
  float4 a = *(const float4*)in;
  us4 o;
  o[0] = f2bf(a.x); o[1] = f2bf(a.y); o[2] = f2bf(a.z); o[3] = f2bf(a.w);
  *(us4*)out = o;
}

__global__ __launch_bounds__(256) void gemm_fused(const us* __restrict__ A,
                                                  const us* __restrict__ B,
                                                  unsigned* __restrict__ cv,
                                                  float* __restrict__ cp,
                                                  float* __restrict__ ch) {
  __shared__ __align__(16) us smem[BM * BK + BN * BK];
  us* As = smem;
  us* Bs = smem + BM * BK;
  unsigned* T = (unsigned*)smem;

  const int tid  = threadIdx.x;
  const int lane = tid & 63;
  const int w    = tid >> 6;
  const int wm   = w & 1;
  const int wn   = w >> 1;
  const long bm  = (long)blockIdx.x * BM;
  const int  d0  = blockIdx.y * 64;

  const int srow = lane >> 3;
  const int sseg = (lane & 7) ^ srow;
  const int fr = lane & 15;
  const int fq = lane >> 4;

  int aoff[4][2], boff[4][2];
#pragma unroll
  for (int mt = 0; mt < 4; ++mt) {
    int row = wm * 64 + mt * 16 + fr;
#pragma unroll
    for (int kk = 0; kk < 2; ++kk) {
      int seg = kk * 4 + fq;
      aoff[mt][kk] = row * BK + ((seg ^ (row & 7)) * 8);
    }
  }
#pragma unroll
  for (int nt = 0; nt < 4; ++nt) {
    int row = wn * 64 + nt * 16 + fr;
#pragma unroll
    for (int kk = 0; kk < 2; ++kk) {
      int seg = kk * 4 + fq;
      boff[nt][kk] = row * BK + ((seg ^ (row & 7)) * 8);
    }
  }

  f4v acc[4][4] = {};

  const us* Ap[4];
  const us* Bp[4];
#pragma unroll
  for (int i = 0; i < 4; ++i) {
    int lr = w * 32 + i * 8 + srow;
    Ap[i] = A + (bm + lr) * (long)KK + sseg * 8;
    int wrow = d0 + ((lr >> 5) << 4) + (lr & 15) + (((lr >> 4) & 1) << 10);
    Bp[i] = B + (long)wrow * KK + sseg * 8;
  }

  for (int kt = 0; kt < KK / BK; ++kt) {
    __syncthreads();
#pragma unroll
    for (int i = 0; i < 4; ++i) {
      GLD16(Ap[i], &As[(w * 32 + i * 8) * BK]);
      GLD16(Bp[i], &Bs[(w * 32 + i * 8) * BK]);
      Ap[i] += BK;
      Bp[i] += BK;
    }
    __syncthreads();

#pragma unroll
    for (int kk = 0; kk < 2; ++kk) {
      s8v af[4], bf[4];
#pragma unroll
      for (int mt = 0; mt < 4; ++mt) af[mt] = *(const s8v*)&As[aoff[mt][kk]];
#pragma unroll
      for (int nt = 0; nt < 4; ++nt) bf[nt] = *(const s8v*)&Bs[boff[nt][kk]];
#pragma unroll
      for (int mt = 0; mt < 4; ++mt)
#pragma unroll
        for (int nt = 0; nt < 4; ++nt)
          acc[mt][nt] = __builtin_amdgcn_mfma_f32_16x16x32_bf16(
              af[mt], bf[nt], acc[mt][nt], 0, 0, 0);
    }
  }

  __syncthreads();
#pragma unroll
  for (int mt = 0; mt < 4; ++mt) {
    int lr0 = wm * 64 + mt * 16 + fq * 4;
#pragma unroll
    for (int p = 0; p < 2; ++p) {
      int ld = (wn * 2 + p) * 16 + fr;
      f4v hv = acc[mt][2 * p];
      f4v gv = acc[mt][2 * p + 1];
#pragma unroll
      for (int r = 0; r < 4; ++r) {
        float coef, v;
        gate_cv(hv[r], gv[r], coef, v);
        pk2 pk = __builtin_amdgcn_cvt_pkrtz(coef, v);
        T[(lr0 + r) * 64 + ld] = __builtin_bit_cast(unsigned, pk);
      }
    }
  }
  __syncthreads();

#pragma unroll
  for (int j = 0; j < 8; ++j) {
    int chunk = j * 256 + tid;
    int row = chunk >> 4;
    int q   = chunk & 15;
    uint4 val = *(const uint4*)&T[row * 64 + q * 4];
    *(uint4*)(cv + (size_t)(bm + row) * DD + d0 + q * 4) = val;
  }

  {
    const int d = tid & 63;
    const int c = tid >> 6;
    float P = 1.0f, h = 0.0f;
#pragma unroll
    for (int i = 0; i < CHUNK; ++i) {
      unsigned u = T[(c * CHUNK + i) * 64 + d];
      __half2 hv = *(__half2*)&u;
      float cf = __half2float(hv.x);
      h = fmaf(cf, h, __half2float(hv.y));
      P *= cf;
    }
    const int b  = (int)(bm / SS);
    const int cg2 = (int)((bm % SS) / CHUNK) + c;
    const int idx = cg2 * BDD + b * DD + d0 + d;
    cp[idx] = P;
    ch[idx] = h;
  }
}

__global__ __launch_bounds__(256) void scan_pass2(const float* __restrict__ cp,
                                                  const float* __restrict__ ch,
                                                  float* __restrict__ carry) {
  const int bd = blockIdx.x * 256 + threadIdx.x;
  float h = 0.0f;
  for (int cb = 0; cb < NC; cb += 16) {
    float p[16], v[16];
#pragma unroll
    for (int i = 0; i < 16; ++i) {
      p[i] = cp[(cb + i) * BDD + bd];
      v[i] = ch[(cb + i) * BDD + bd];
    }
#pragma unroll
    for (int i = 0; i < 16; ++i) {
      carry[(cb + i) * BDD + bd] = h;
      h = fmaf(p[i], h, v[i]);
    }
  }
}

__global__ __launch_bounds__(256) void scan_pass3(const uint4* __restrict__ cv,
                                                  const float* __restrict__ carry,
                                                  float4* __restrict__ out) {
  const int q = threadIdx.x;
  const int c = blockIdx.y;
  const int b = blockIdx.z;
  const size_t rbase = ((size_t)b * SS + (size_t)c * CHUNK) * DQ + q;
  const uint4* base = cv + rbase;
  float4* obase = out + rbase;
  float4 h = *(const float4*)&carry[c * BDD + b * DD + 4 * q];
  for (int tb = 0; tb < CHUNK; tb += 8) {
    uint4 u[8];
#pragma unroll
    for (int j = 0; j < 8; ++j) u[j] = base[(size_t)(tb + j) * DQ];
#pragma unroll
    for (int j = 0; j < 8; ++j) {
      __half2 a0 = *(__half2*)&u[j].x;
      __half2 a1 = *(__half2*)&u[j].y;
      __half2 a2 = *(__half2*)&u[j].z;
      __half2 a3 = *(__half2*)&u[j].w;
      h.x = fmaf(__half2float(a0.x), h.x, __half2float(a0.y));
      h.y = fmaf(__half2float(a1.x), h.y, __half2float(a1.y));
      h.z = fmaf(__half2float(a2.x), h.z, __half2float(a2.y));
      h.w = fmaf(__half2float(a3.x), h.w, __half2float(a3.y));
      obase[(size_t)(tb + j) * DQ] = h;
    }
  }
}

// ---------- launch ----------
extern "C" void kernel_launch(void* const* d_in, const int* in_sizes, int n_in,
                              void* d_out, int out_size, void* d_ws, size_t ws_size,
                              hipStream_t stream) {
  const float* x = (const float*)d_in[0];   // [4,4096,1024] fp32
  const float* W = (const float*)d_in[1];   // [2048,1024]  fp32

  const long nx = (long)MM * KK;            // 16,777,216
  const long nw = (long)NN * KK;            //  2,097,152

  // workspace layout (~106 MiB total)
  char* ws = (char*)d_ws;
  unsigned* cv = (unsigned*)ws;      ws += (size_t)MM * DD * sizeof(unsigned); // 64 MiB
  us* xb = (us*)ws;                  ws += (size_t)nx * sizeof(us);            // 32 MiB
  us* wb = (us*)ws;                  ws += (size_t)nw * sizeof(us);            //  4 MiB
  float* cp = (float*)ws;            ws += (size_t)NC * BDD * sizeof(float);   //  2 MiB
  float* chh = (float*)ws;           ws += (size_t)NC * BDD * sizeof(float);   //  2 MiB
  float* carry = (float*)ws;         ws += (size_t)NC * BDD * sizeof(float);   //  2 MiB

  // one-time cooperative capability + occupancy probe (host-only queries,
  // no stream ops -> graph-capture-safe)
  static int s_coop = -1;
  if (s_coop < 0) {
    s_coop = 0;
    int dev = 0;
    hipGetDevice(&dev);
    hipDeviceProp_t prop{};
    if (hipGetDeviceProperties(&prop, dev) == hipSuccess && prop.cooperativeLaunch) {
      int perCU = 0;
      if (hipOccupancyMaxActiveBlocksPerMultiprocessor(
              &perCU, (const void*)mega, 256, 0) == hipSuccess && perCU >= 1) {
        long cap = (long)perCU * prop.multiProcessorCount;
        s_coop = (int)(cap < 2048 ? cap : 2048);
      }
    }
    if (s_coop < 16) s_coop = 0;   // need >=4096 threads for phase 3
  }

  if (s_coop > 0) {
    const float* xl = x; const float* Wl = W;
    us* xbl = xb; us* wbl = wb;
    unsigned* cvl = cv;
    float* cpl = cp; float* chl = chh; float* cal = carry;
    float2* outl = (float2*)d_out;
    void* args[] = {&xl, &Wl, &xbl, &wbl, &cvl, &cpl, &chl, &cal, &outl};
    if (hipLaunchCooperativeKernel((void*)mega, dim3(s_coop), dim3(256),
                                   args, 0, stream) == hipSuccess)
      return;
    s_coop = 0;   // launch rejected: don't retry, fall through
  }

  // fallback: proven R5 four-kernel pipeline
  cvt_both<<<(int)((nx + nw) / 4 / 256), 256, 0, stream>>>(x, W, xb, wb, nx);
  gemm_fused<<<dim3(MM / BM, DD / 64), 256, 0, stream>>>(xb, wb, cv, cp, chh);
  scan_pass2<<<dim3(BDD / 256), 256, 0, stream>>>(cp, chh, carry);
  scan_pass3<<<dim3(1, NC, BB), 256, 0, stream>>>((const uint4*)cv, carry,
                                                  (float4*)d_out);
}

// Round 8
// 221.856 us; speedup vs baseline: 2.3063x; 1.0114x over previous
//
#include <hip/hip_runtime.h>
#include <hip/hip_bf16.h>
#include <hip/hip_fp16.h>
#include <cstdint>

// ---------- types ----------
typedef unsigned short us;
typedef us   us4 __attribute__((ext_vector_type(4)));
typedef short s8v __attribute__((ext_vector_type(8)));   // 8 bf16 (4 VGPRs) MFMA A/B frag
typedef float f4v __attribute__((ext_vector_type(4)));   // MFMA C/D frag
typedef __fp16 pk2 __attribute__((ext_vector_type(2))); // cvt_pkrtz result type

// Problem constants (B=4, S=4096, D=1024 fixed by setup_inputs)
#define BB 4
#define SS 4096
#define DD 1024
#define MM (BB * SS)      // 16384
#define NN (2 * DD)       // 2048
#define KK DD             // 1024

// GEMM tiling (measured-best 128^2 2-phase structure; 256^2 8-phase and the
// cooperative mega-kernel both regressed and are retired: the 8-phase
// schedule didn't transfer to this shape, and cooperative launches are
// rejected by the harness's graph capture — R7's timed run was the fallback.)
#define BM 128
#define BN 128
#define BK 64

// Scan chunking
#define CHUNK 32
#define NC (SS / CHUNK)   // 128
#define BDD (BB * DD)     // 4096 sequences
#define DP (DD / 2)       // 512 channel-pairs (pass3)

// ---------- fp32 -> bf16 (RNE) ----------
__device__ inline us f2bf(float f) {
  unsigned u = __float_as_uint(f);
  u += 0x7fffu + ((u >> 16) & 1u);
  return (us)(u >> 16);
}

// one launch converts both x and W (x occupies the first nx/4 quads).
__global__ __launch_bounds__(256) void cvt_both(const float* __restrict__ x,
                                                const float* __restrict__ W,
                                                us* __restrict__ xb,
                                                us* __restrict__ wb,
                                                long nx) {
  long i = ((long)blockIdx.x * 256 + threadIdx.x) * 4;
  const float* in;
  us* out;
  if (i < nx) { in = x + i; out = xb + i; }
  else        { in = W + (i - nx); out = wb + (i - nx); }
  float4 a = *(const float4*)in;
  us4 o;
  o[0] = f2bf(a.x); o[1] = f2bf(a.y); o[2] = f2bf(a.z); o[3] = f2bf(a.w);
  *(us4*)out = o;
}

// ---------- async global->LDS, 16B per lane ----------
#define GLD16(g, l)                                                        \
  __builtin_amdgcn_global_load_lds(                                        \
      (const __attribute__((address_space(1))) void*)(g),                  \
      (__attribute__((address_space(3))) void*)(l), 16, 0, 0)

// ---------- gate math ----------
// h_t = coef*h_{t-1} + v ;  coef = sigmoid(-gate), v = sigmoid(gate)*g(hidden)
// g(x) = x+0.5 (x>=0) else sigmoid(x). Fast: v_exp + v_rcp (1 ulp), no divides.
__device__ inline void gate_cv(float hid, float gat, float& coef, float& v) {
  float e = __expf(gat);
  coef = __builtin_amdgcn_rcpf(1.0f + e);      // sigmoid(-gate)
  float z = 1.0f - coef;                        // sigmoid(gate), robust at e=inf
  float eh = __expf(hid < 0.0f ? hid : 0.0f);   // only meaningful on neg path
  float gneg = eh * __builtin_amdgcn_rcpf(1.0f + eh);  // eh<=1: safe
  float g = (hid >= 0.0f) ? (hid + 0.5f) : gneg;
  v = z * g;
}

// ---------- fused GEMM + gate epilogue + chunk-local scan (pass1) ----------
// (R1 structure, measured 91-93us.) Block covers 128 consecutive rows
// (= 4 chunks of 32 t's within one batch b) x 64 output channels [d0,d0+64).
// R8: cv now points INTO d_out (64 MiB aliased away from the workspace;
// pass3 consumes it in place). gemm itself is byte-identical to R5.
__global__ __launch_bounds__(256) void gemm_fused(const us* __restrict__ A,
                                                  const us* __restrict__ B,
                                                  unsigned* __restrict__ cv,
                                                  float* __restrict__ cp,
                                                  float* __restrict__ ch) {
  __shared__ __align__(16) us smem[BM * BK + BN * BK];  // 32 KB
  us* As = smem;
  us* Bs = smem + BM * BK;
  unsigned* T = (unsigned*)smem;    // epilogue reuse: [128 rows][64 d] uint

  const int tid  = threadIdx.x;
  const int lane = tid & 63;
  const int w    = tid >> 6;      // wave 0..3
  const int wm   = w & 1;         // 2x2 wave grid
  const int wn   = w >> 1;
  const long bm  = (long)blockIdx.x * BM;
  const int  d0  = blockIdx.y * 64;

  // staging: each global_load_lds covers 8 rows x 64 cols (1 KiB)
  const int srow = lane >> 3;                 // row within 8-row group
  const int sseg = (lane & 7) ^ srow;         // XOR-permuted source segment

  const int fr = lane & 15;
  const int fq = lane >> 4;                   // 0..3

  int aoff[4][2], boff[4][2];
#pragma unroll
  for (int mt = 0; mt < 4; ++mt) {
    int row = wm * 64 + mt * 16 + fr;
#pragma unroll
    for (int kk = 0; kk < 2; ++kk) {
      int seg = kk * 4 + fq;
      aoff[mt][kk] = row * BK + ((seg ^ (row & 7)) * 8);
    }
  }
#pragma unroll
  for (int nt = 0; nt < 4; ++nt) {
    int row = wn * 64 + nt * 16 + fr;
#pragma unroll
    for (int kk = 0; kk < 2; ++kk) {
      int seg = kk * 4 + fq;
      boff[nt][kk] = row * BK + ((seg ^ (row & 7)) * 8);
    }
  }

  f4v acc[4][4] = {};

  const us* Ap[4];
  const us* Bp[4];
#pragma unroll
  for (int i = 0; i < 4; ++i) {
    int lr = w * 32 + i * 8 + srow;           // local tile row
    Ap[i] = A + (bm + lr) * (long)KK + sseg * 8;
    int wrow = d0 + ((lr >> 5) << 4) + (lr & 15) + (((lr >> 4) & 1) << 10);
    Bp[i] = B + (long)wrow * KK + sseg * 8;
  }

  for (int kt = 0; kt < KK / BK; ++kt) {
    __syncthreads();   // previous tile's reads done before overwrite
#pragma unroll
    for (int i = 0; i < 4; ++i) {
      GLD16(Ap[i], &As[(w * 32 + i * 8) * BK]);
      GLD16(Bp[i], &Bs[(w * 32 + i * 8) * BK]);
      Ap[i] += BK;
      Bp[i] += BK;
    }
    __syncthreads();   // staging visible

#pragma unroll
    for (int kk = 0; kk < 2; ++kk) {
      s8v af[4], bf[4];
#pragma unroll
      for (int mt = 0; mt < 4; ++mt) af[mt] = *(const s8v*)&As[aoff[mt][kk]];
#pragma unroll
      for (int nt = 0; nt < 4; ++nt) bf[nt] = *(const s8v*)&Bs[boff[nt][kk]];
#pragma unroll
      for (int mt = 0; mt < 4; ++mt)
#pragma unroll
        for (int nt = 0; nt < 4; ++nt)
          acc[mt][nt] = __builtin_amdgcn_mfma_f32_16x16x32_bf16(
              af[mt], bf[nt], acc[mt][nt], 0, 0, 0);
    }
  }

  // ---- epilogue ----
  __syncthreads();   // all waves done with As/Bs; reuse LDS as T
  // C/D row = fq*4 + r, col = fr (m89 layout); hid/gate pair = (nt=2p, 2p+1)
#pragma unroll
  for (int mt = 0; mt < 4; ++mt) {
    int lr0 = wm * 64 + mt * 16 + fq * 4;     // local row base
#pragma unroll
    for (int p = 0; p < 2; ++p) {
      int ld = (wn * 2 + p) * 16 + fr;        // local d
      f4v hv = acc[mt][2 * p];
      f4v gv = acc[mt][2 * p + 1];
#pragma unroll
      for (int r = 0; r < 4; ++r) {
        float coef, v;
        gate_cv(hv[r], gv[r], coef, v);
        pk2 pk = __builtin_amdgcn_cvt_pkrtz(coef, v);   // (lo=coef, hi=v)
        T[(lr0 + r) * 64 + ld] = __builtin_bit_cast(unsigned, pk);
      }
    }
  }
  __syncthreads();   // transpose complete

  // (1) coalesced cv writes: 2048 uint4 chunks (128 rows x 16), 8 per thread
#pragma unroll
  for (int j = 0; j < 8; ++j) {
    int chunk = j * 256 + tid;
    int row = chunk >> 4;                     // 0..127
    int q   = chunk & 15;                     // 16B chunk within row
    uint4 val = *(const uint4*)&T[row * 64 + q * 4];
    *(uint4*)(cv + (size_t)(bm + row) * DD + d0 + q * 4) = val;
  }

  // (2) chunk-local scan: thread -> (local chunk c = tid>>6, d = tid&63)
  {
    const int d = tid & 63;
    const int c = tid >> 6;                   // 0..3
    float P = 1.0f, h = 0.0f;
#pragma unroll
    for (int i = 0; i < CHUNK; ++i) {
      unsigned u = T[(c * CHUNK + i) * 64 + d];
      __half2 hv = *(__half2*)&u;
      float cf = __half2float(hv.x);
      h = fmaf(cf, h, __half2float(hv.y));
      P *= cf;
    }
    const int b  = (int)(bm / SS);
    const int cg = (int)((bm % SS) / CHUNK) + c;   // global chunk 0..127
    const int idx = cg * BDD + b * DD + d0 + d;    // [chunk][b][d]
    cp[idx] = P;
    ch[idx] = h;
  }
}

// pass2: serial scan over NC chunk summaries per sequence; 4096 threads.
// (R1 version, measured-best: 16-deep load batching for ILP.)
__global__ __launch_bounds__(256) void scan_pass2(const float* __restrict__ cp,
                                                  const float* __restrict__ ch,
                                                  float* __restrict__ carry) {
  const int bd = blockIdx.x * 256 + threadIdx.x;  // 0..4095
  float h = 0.0f;
  for (int cb = 0; cb < NC; cb += 16) {
    float p[16], v[16];
#pragma unroll
    for (int i = 0; i < 16; ++i) {
      p[i] = cp[(cb + i) * BDD + bd];
      v[i] = ch[(cb + i) * BDD + bd];
    }
#pragma unroll
    for (int i = 0; i < 16; ++i) {
      carry[(cb + i) * BDD + bd] = h;               // carry INTO chunk cb+i
      h = fmaf(p[i], h, v[i]);
    }
  }
}

// pass3 (R8): IN-PLACE — cv aliases d_out, so this kernel reads its chunk's
// half2 (coef,v) rows and overwrites the same addresses with fp32 h.
// NO __restrict__ on cv/out (they alias). Safety: each thread owns one
// channel-pair column; ALL 32 loads are issued before any store (program
// order; compiler cannot sink stores above possibly-aliasing loads), and
// thread/block regions are disjoint. fma order per channel identical to R5
// -> bit-identical out. 1024 blocks (4/CU, was 2/CU) + full-depth preload.
__global__ __launch_bounds__(256) void scan_pass3(const uint2* cv,
                                                  const float* __restrict__ carry,
                                                  float2* out) {
  const int dp = blockIdx.x * 256 + threadIdx.x;  // 0..511 channel-pair
  const int c = blockIdx.y;
  const int b = blockIdx.z;
  const size_t rbase = ((size_t)b * SS + (size_t)c * CHUNK) * DP + dp;
  const uint2* base = cv + rbase;
  float2* obase = out + rbase;
  float2 h = *(const float2*)&carry[c * BDD + b * DD + 2 * dp];

  uint2 u[CHUNK];
#pragma unroll
  for (int t = 0; t < CHUNK; ++t) u[t] = base[(size_t)t * DP];   // all loads first
#pragma unroll
  for (int t = 0; t < CHUNK; ++t) {
    __half2 a  = *(__half2*)&u[t].x;
    __half2 bq = *(__half2*)&u[t].y;
    h.x = fmaf(__half2float(a.x),  h.x, __half2float(a.y));
    h.y = fmaf(__half2float(bq.x), h.y, __half2float(bq.y));
    obase[(size_t)t * DP] = h;
  }
}

// ---------- launch ----------
extern "C" void kernel_launch(void* const* d_in, const int* in_sizes, int n_in,
                              void* d_out, int out_size, void* d_ws, size_t ws_size,
                              hipStream_t stream) {
  const float* x = (const float*)d_in[0];   // [4,4096,1024] fp32
  const float* W = (const float*)d_in[1];   // [2048,1024]  fp32

  const long nx = (long)MM * KK;            // 16,777,216
  const long nw = (long)NN * KK;            //  2,097,152

  // R8: cv lives in d_out (same 64 MiB footprint as the fp32 output; pass3
  // consumes it in place). Workspace shrinks 106 -> 42 MiB.
  unsigned* cv = (unsigned*)d_out;

  char* ws = (char*)d_ws;
  us* xb = (us*)ws;                  ws += (size_t)nx * sizeof(us);            // 32 MiB
  us* wb = (us*)ws;                  ws += (size_t)nw * sizeof(us);            //  4 MiB
  float* cp = (float*)ws;            ws += (size_t)NC * BDD * sizeof(float);   //  2 MiB
  float* chh = (float*)ws;           ws += (size_t)NC * BDD * sizeof(float);   //  2 MiB
  float* carry = (float*)ws;         ws += (size_t)NC * BDD * sizeof(float);   //  2 MiB

  cvt_both<<<(int)((nx + nw) / 4 / 256), 256, 0, stream>>>(x, W, xb, wb, nx);

  gemm_fused<<<dim3(MM / BM, DD / 64), 256, 0, stream>>>(xb, wb, cv, cp, chh);

  scan_pass2<<<dim3(BDD / 256), 256, 0, stream>>>(cp, chh, carry);
  scan_pass3<<<dim3(DP / 256, NC, BB), 256, 0, stream>>>((const uint2*)cv, carry,
                                                         (float2*)d_out);
}